// Round 6
// baseline (4025.333 us; speedup 1.0000x reference)
//
#include <hip/hip_runtime.h>

// ---------------------------------------------------------------------------
// HeadsSelection: emb-gather -> 2x bidirectional LSTM -> additive attention
// S=256, B=16, V=20000, E=512, H=256, L=2, HM=128
// Round 6: XCD-local L2 exchange for the recurrence.
//   - 512 WGs launched; each reads its XCC_ID (s_getreg, HW-verified) and
//     claims a role: XCD0 -> dir 0 (16 slots), XCD1 -> dir 1; rest exit.
//     Timed rescue path fills unclaimed slots from any XCD (no deadlock).
//   - Producers publish h twice: plain store (dirty in local XCD L2 = fast
//     path, ~200cy RT) + relaxed agent/sc1 store (LLC = safety net). Same
//     value, so any write ordering / eviction interleaving is benign.
//   - Consumers poll with global_load_dwordx2 sc0 (L1-bypass, L2-served)
//     asm bundles; every 8th retry round falls back to agent-scope (LLC)
//     loads so cross-XCD members (rescue case) still make progress.
//   - Compute body = R4's proven 32 WG x 256 thr split-bf16 MFMA.
// ---------------------------------------------------------------------------

#define S_    256
#define B_    16
#define E_    512
#define H_    256
#define HM_   128
#define M_    4096   // S*B

typedef __attribute__((ext_vector_type(8))) short short8;
typedef __attribute__((ext_vector_type(4))) float f32x4;

__device__ __forceinline__ float sigm(float x) { return 1.f / (1.f + __expf(-x)); }
__device__ __forceinline__ float tanh_fast(float x) {
  x = fminf(fmaxf(x, -15.f), 15.f);
  float e = __expf(2.f * x);
  return (e - 1.f) / (e + 1.f);
}
__device__ __forceinline__ unsigned short f2bf(float f) {
  unsigned u = __float_as_uint(f);
  u += 0x7FFFu + ((u >> 16) & 1u);
  return (unsigned short)(u >> 16);
}
__device__ __forceinline__ float bf2f(unsigned short s) {
  return __uint_as_float(((unsigned)s) << 16);
}

// 16 x u64 loads, L1-bypass / L2-served (sc0). p1 = p0 + 512 entries.
__device__ __forceinline__ void load16_sc0(unsigned long long v[16],
                                           const unsigned long long* p0,
                                           const unsigned long long* p1) {
  asm volatile(
      "global_load_dwordx2 %0, %16, off sc0\n\t"
      "global_load_dwordx2 %1, %16, off offset:512 sc0\n\t"
      "global_load_dwordx2 %2, %16, off offset:1024 sc0\n\t"
      "global_load_dwordx2 %3, %16, off offset:1536 sc0\n\t"
      "global_load_dwordx2 %4, %16, off offset:2048 sc0\n\t"
      "global_load_dwordx2 %5, %16, off offset:2560 sc0\n\t"
      "global_load_dwordx2 %6, %16, off offset:3072 sc0\n\t"
      "global_load_dwordx2 %7, %16, off offset:3584 sc0\n\t"
      "global_load_dwordx2 %8, %17, off sc0\n\t"
      "global_load_dwordx2 %9, %17, off offset:512 sc0\n\t"
      "global_load_dwordx2 %10, %17, off offset:1024 sc0\n\t"
      "global_load_dwordx2 %11, %17, off offset:1536 sc0\n\t"
      "global_load_dwordx2 %12, %17, off offset:2048 sc0\n\t"
      "global_load_dwordx2 %13, %17, off offset:2560 sc0\n\t"
      "global_load_dwordx2 %14, %17, off offset:3072 sc0\n\t"
      "global_load_dwordx2 %15, %17, off offset:3584 sc0\n\t"
      "s_waitcnt vmcnt(0)"
      : "=&v"(v[0]), "=&v"(v[1]), "=&v"(v[2]), "=&v"(v[3]),
        "=&v"(v[4]), "=&v"(v[5]), "=&v"(v[6]), "=&v"(v[7]),
        "=&v"(v[8]), "=&v"(v[9]), "=&v"(v[10]), "=&v"(v[11]),
        "=&v"(v[12]), "=&v"(v[13]), "=&v"(v[14]), "=&v"(v[15])
      : "v"(p0), "v"(p1)
      : "memory");
}

// ---------------------------------------------------------------- gather ----
__global__ void k_gather(const int* __restrict__ concepts, const float* __restrict__ emb,
                         float* __restrict__ X) {
  int m = blockIdx.x;                       // m = s*16 + b
  int tok = concepts[m];
  const float4* src = reinterpret_cast<const float4*>(emb + (size_t)tok * E_);
  float4* dst = reinterpret_cast<float4*>(X + (size_t)m * E_);
  for (int i = threadIdx.x; i < E_ / 4; i += blockDim.x) dst[i] = src[i];
}

// ------------------------------------------------------------------ GEMM ----
// C[m][n] = sum_k A[m][k] * W[n][k] + bias[n], row-major C[m*N + n]
__global__ __launch_bounds__(256) void k_gemm(const float* __restrict__ A,
                                              const float* __restrict__ W,
                                              const float* __restrict__ bias,
                                              float* __restrict__ C,
                                              int M, int N, int K) {
  __shared__ __align__(16) float As[16][132];
  __shared__ __align__(16) float Ws[16][132];
  const int bm = blockIdx.x * 128, bn = blockIdx.y * 128;
  const int tid = threadIdx.x;
  const int tm = (tid >> 4) * 8, tn = (tid & 15) * 8;
  float acc[8][8];
#pragma unroll
  for (int i = 0; i < 8; i++)
#pragma unroll
    for (int j = 0; j < 8; j++) acc[i][j] = 0.f;

  const int lr = tid >> 1, lk = (tid & 1) * 8;
  for (int k0 = 0; k0 < K; k0 += 16) {
    float4 a0 = *(const float4*)(A + (size_t)(bm + lr) * K + k0 + lk);
    float4 a1 = *(const float4*)(A + (size_t)(bm + lr) * K + k0 + lk + 4);
    float4 w0 = *(const float4*)(W + (size_t)(bn + lr) * K + k0 + lk);
    float4 w1 = *(const float4*)(W + (size_t)(bn + lr) * K + k0 + lk + 4);
    As[lk + 0][lr] = a0.x; As[lk + 1][lr] = a0.y; As[lk + 2][lr] = a0.z; As[lk + 3][lr] = a0.w;
    As[lk + 4][lr] = a1.x; As[lk + 5][lr] = a1.y; As[lk + 6][lr] = a1.z; As[lk + 7][lr] = a1.w;
    Ws[lk + 0][lr] = w0.x; Ws[lk + 1][lr] = w0.y; Ws[lk + 2][lr] = w0.z; Ws[lk + 3][lr] = w0.w;
    Ws[lk + 4][lr] = w1.x; Ws[lk + 5][lr] = w1.y; Ws[lk + 6][lr] = w1.z; Ws[lk + 7][lr] = w1.w;
    __syncthreads();
#pragma unroll
    for (int k = 0; k < 16; k++) {
      float4 av0 = *(const float4*)&As[k][tm];
      float4 av1 = *(const float4*)&As[k][tm + 4];
      float4 wv0 = *(const float4*)&Ws[k][tn];
      float4 wv1 = *(const float4*)&Ws[k][tn + 4];
      float a[8] = {av0.x, av0.y, av0.z, av0.w, av1.x, av1.y, av1.z, av1.w};
      float w[8] = {wv0.x, wv0.y, wv0.z, wv0.w, wv1.x, wv1.y, wv1.z, wv1.w};
#pragma unroll
      for (int i = 0; i < 8; i++)
#pragma unroll
        for (int j = 0; j < 8; j++) acc[i][j] += a[i] * w[j];
    }
    __syncthreads();
  }

  float bv[8];
#pragma unroll
  for (int j = 0; j < 8; j++) bv[j] = bias ? bias[bn + tn + j] : 0.f;
#pragma unroll
  for (int i = 0; i < 8; i++) {
    float4 v0 = make_float4(acc[i][0] + bv[0], acc[i][1] + bv[1], acc[i][2] + bv[2], acc[i][3] + bv[3]);
    float4 v1 = make_float4(acc[i][4] + bv[4], acc[i][5] + bv[5], acc[i][6] + bv[6], acc[i][7] + bv[7]);
    *(float4*)(C + (size_t)(bm + tm + i) * N + bn + tn) = v0;
    *(float4*)(C + (size_t)(bm + tm + i) * N + bn + tn + 4) = v1;
  }
}

// ------------------------------------------------------------- LSTM layer ----
// 512 WGs launched, 32 claim roles: dir(2) x g(16); WG (d,g) owns units
// [g*16,(g+1)*16), i.e. gate rows q*256 + g*16 + [0,16), all 16 batches.
// Wave q = gate q, one 16x16 MFMA tile, K=256 (split-bf16 3-product).
// Gin: [m][2048] row-major; Hout: [m][512]; Hbuf: [d][parity][b][unit] u64
// {stamp:32, packed h hi/lo bf16:32}.
__global__ __launch_bounds__(256) void k_lstm(const float* __restrict__ Gin,
                                              const float* __restrict__ whh,
                                              float* __restrict__ Hout,
                                              unsigned long long* __restrict__ Hbuf,
                                              int* __restrict__ cnt) {
  __shared__ int s_role;
  if (threadIdx.x == 0) {
    unsigned xcc;
    asm volatile("s_getreg_b32 %0, hwreg(HW_REG_XCC_ID)" : "=s"(xcc));
    xcc &= 7u;
    int role = -1;
    if (xcc <= 1u) {
      int slot = __hip_atomic_fetch_add(&cnt[xcc], 1, __ATOMIC_RELAXED,
                                        __HIP_MEMORY_SCOPE_AGENT);
      if (slot < 16) role = ((int)xcc << 4) | slot;
    }
    if (role < 0) {
      // rescue: exit once both dirs filled; after a grace period, claim
      // leftovers from any XCD (keeps liveness if placement is pathological)
      long long t0 = clock64();
      for (;;) {
        int c0 = __hip_atomic_load(&cnt[0], __ATOMIC_RELAXED, __HIP_MEMORY_SCOPE_AGENT);
        int c1 = __hip_atomic_load(&cnt[1], __ATOMIC_RELAXED, __HIP_MEMORY_SCOPE_AGENT);
        if (c0 >= 16 && c1 >= 16) break;
        if (clock64() - t0 > 400000) {
          int dd = (c0 < 16) ? 0 : 1;
          int slot = __hip_atomic_fetch_add(&cnt[dd], 1, __ATOMIC_RELAXED,
                                            __HIP_MEMORY_SCOPE_AGENT);
          if (slot < 16) { role = (dd << 4) | slot; break; }
        } else {
          __builtin_amdgcn_s_sleep(32);
        }
      }
    }
    s_role = role;
  }
  __syncthreads();
  const int role = s_role;
  if (role < 0) return;
  const int d = role >> 4;
  const int g = role & 15;

  const int tid = threadIdx.x;
  const int q = tid >> 6;          // wave index = gate index (i,f,g,o)
  const int lane = tid & 63;
  const int bcol = lane & 15;      // MFMA A row / C col (batch)
  const int quad = lane >> 4;      // MFMA k-group / C row group
  const int u_e = tid & 15;        // epilogue: unit
  const int b_e = tid >> 4;        // epilogue: batch
  __shared__ unsigned int hL[16 * 260];           // packed h: [b]*260 + [k]
  __shared__ __align__(16) float Lg[4][16][24];   // [gate][b][unit(+pad)]

  // ---- one-time: A fragments (whh) into VGPRs, split bf16 main+residual ----
  unsigned int Am[8][4], Ar[8][4];
  {
    const float* wrow = whh + (size_t)((d << 10) + (q << 8) + (g << 4) + bcol) * 256;
#pragma unroll
    for (int s = 0; s < 8; ++s) {
      float w[8];
      *(float4*)&w[0] = *(const float4*)(wrow + s * 32 + quad * 8);
      *(float4*)&w[4] = *(const float4*)(wrow + s * 32 + quad * 8 + 4);
#pragma unroll
      for (int j = 0; j < 4; ++j) {
        unsigned short m0 = f2bf(w[2 * j]), m1 = f2bf(w[2 * j + 1]);
        unsigned short r0 = f2bf(w[2 * j] - bf2f(m0));
        unsigned short r1 = f2bf(w[2 * j + 1] - bf2f(m1));
        Am[s][j] = (unsigned)m0 | ((unsigned)m1 << 16);
        Ar[s][j] = (unsigned)r0 | ((unsigned)r1 << 16);
      }
    }
  }

  float c_reg = 0.f;
  for (int it = 0; it < 256; ++it) {
    const int step = d ? (255 - it) : it;

    // ---- Gin prefetch (independent of h) ----
    float gin[4];
#pragma unroll
    for (int qq = 0; qq < 4; ++qq)
      gin[qq] = Gin[((size_t)((step << 4) + b_e) << 11) + (d << 10) + (qq << 8) + (g << 4) + u_e];

    // ---- stage h_prev: sc0 (L2) loads, stamp-retry; sc1 fallback rounds ----
    if (it > 0) {
      const unsigned long long* src = Hbuf + ((size_t)((d << 1) + ((it - 1) & 1)) << 12);
      const unsigned long long* p0 = src + (q << 10) + lane;   // entries base
      const unsigned long long* p1 = p0 + 512;
      const unsigned int want = (unsigned int)it;
      unsigned long long v[16];
      load16_sc0(v, p0, p1);
      int round = 0;
      for (;;) {
        unsigned int badm = 0;
#pragma unroll
        for (int c = 0; c < 16; ++c)
          badm |= ((unsigned int)(v[c] >> 32) != want) ? (1u << c) : 0u;
        if (__ballot(badm != 0) == 0ull) break;
        ++round;
        if ((round & 7) == 0) {
          // LLC safety rounds: see cross-XCD producers (rescue placements)
#pragma unroll
          for (int c = 0; c < 16; ++c)
            if (badm & (1u << c))
              v[c] = __hip_atomic_load(p0 + (c << 6), __ATOMIC_RELAXED,
                                       __HIP_MEMORY_SCOPE_AGENT);
        } else {
          load16_sc0(v, p0, p1);
        }
      }
#pragma unroll
      for (int c = 0; c < 16; ++c) {
        int e_b = (q << 2) + (c >> 2);             // entry e = q*1024+c*64+lane
        int e_k = ((c & 3) << 6) + lane;           //        = b*256+k
        hL[e_b * 260 + e_k] = (unsigned int)v[c];
      }
    }
    __syncthreads();

    // ---- B fragments from LDS, 3-product split MFMA ----
    f32x4 acc0 = {0.f, 0.f, 0.f, 0.f}, acc1 = acc0, acc2 = acc0;
    if (it > 0) {
#pragma unroll
      for (int s = 0; s < 8; ++s) {
        const unsigned int* p = &hL[bcol * 260 + (s << 5) + (quad << 3)];
        uint4 p0v = *(const uint4*)p;
        uint4 p1v = *(const uint4*)(p + 4);
        union { unsigned int u[4]; short8 v; } Bm, Br, Amu, Aru;
        Bm.u[0] = __builtin_amdgcn_perm(p0v.y, p0v.x, 0x05040100u);
        Br.u[0] = __builtin_amdgcn_perm(p0v.y, p0v.x, 0x07060302u);
        Bm.u[1] = __builtin_amdgcn_perm(p0v.w, p0v.z, 0x05040100u);
        Br.u[1] = __builtin_amdgcn_perm(p0v.w, p0v.z, 0x07060302u);
        Bm.u[2] = __builtin_amdgcn_perm(p1v.y, p1v.x, 0x05040100u);
        Br.u[2] = __builtin_amdgcn_perm(p1v.y, p1v.x, 0x07060302u);
        Bm.u[3] = __builtin_amdgcn_perm(p1v.w, p1v.z, 0x05040100u);
        Br.u[3] = __builtin_amdgcn_perm(p1v.w, p1v.z, 0x07060302u);
#pragma unroll
        for (int j = 0; j < 4; ++j) { Amu.u[j] = Am[s][j]; Aru.u[j] = Ar[s][j]; }
        acc0 = __builtin_amdgcn_mfma_f32_16x16x32_bf16(Amu.v, Bm.v, acc0, 0, 0, 0);
        acc1 = __builtin_amdgcn_mfma_f32_16x16x32_bf16(Amu.v, Br.v, acc1, 0, 0, 0);
        acc2 = __builtin_amdgcn_mfma_f32_16x16x32_bf16(Aru.v, Bm.v, acc2, 0, 0, 0);
      }
    }
    // ---- gate tile -> LDS (C layout: col=bcol=batch, row=quad*4+i=unit) ----
    {
      f32x4 t = acc0 + acc1 + acc2;
      *(float4*)&Lg[q][bcol][quad << 2] = make_float4(t[0], t[1], t[2], t[3]);
    }
    __syncthreads();

    // ---- nonlinearity + state update; double publish (L2 fast + LLC safe) ----
    {
      float gi = Lg[0][b_e][u_e] + gin[0];
      float gf = Lg[1][b_e][u_e] + gin[1];
      float gg = Lg[2][b_e][u_e] + gin[2];
      float go = Lg[3][b_e][u_e] + gin[3];
      float ct = sigm(gf) * c_reg + sigm(gi) * tanh_fast(gg);
      c_reg = ct;
      float h = sigm(go) * tanh_fast(ct);
      unsigned short hm = f2bf(h);
      unsigned short hr = f2bf(h - bf2f(hm));
      unsigned long long hp = ((unsigned long long)(unsigned int)(it + 1) << 32) |
                              (unsigned long long)(((unsigned)hr << 16) | (unsigned)hm);
      unsigned long long* dst =
          Hbuf + ((size_t)((d << 1) + (it & 1)) << 12) + (b_e << 8) + (g << 4) + u_e;
      // plain store -> dirty line in local XCD L2 (fast path for sc0 pollers)
      asm volatile("global_store_dwordx2 %0, %1, off" :: "v"(dst), "v"(hp) : "memory");
      // agent/sc1 store -> LLC (safety net for cross-XCD pollers); same value,
      // so any ordering/eviction interleaving is benign.
      __hip_atomic_store(dst, hp, __ATOMIC_RELAXED, __HIP_MEMORY_SCOPE_AGENT);
      Hout[(size_t)((step << 4) + b_e) * 512 + (d << 8) + (g << 4) + u_e] = h;
    }
    // no drain barrier: consumers validate stamps themselves.
  }
}

// ------------------------------------------------------------- attention ----
// scores[b][i][j] = sum_h va[h]*tanh(P[i*16+b][h] + Cc[j*16+b][h])
// out[0 .. 1M) = scores; out[1M .. 2M) = predictions (sigmoid>=0.5 <=> x>=0)
__global__ __launch_bounds__(256) void k_attn(const float* __restrict__ P,
                                              const float* __restrict__ Cc,
                                              const float* __restrict__ va,
                                              float* __restrict__ out) {
  const int b = blockIdx.x & 15, i = blockIdx.x >> 4;
  __shared__ float pv[128], vv[128];
  const int t = threadIdx.x;
  if (t < 128) {
    pv[t] = P[(size_t)((i << 4) + b) * 128 + t];
    vv[t] = va[t];
  }
  __syncthreads();
  const float4* c4 = reinterpret_cast<const float4*>(Cc + (size_t)((t << 4) + b) * 128);
  float acc = 0.f;
#pragma unroll 8
  for (int hh = 0; hh < 32; ++hh) {
    float4 cv = c4[hh];
    int h = hh << 2;
    acc += vv[h]     * tanh_fast(pv[h]     + cv.x);
    acc += vv[h + 1] * tanh_fast(pv[h + 1] + cv.y);
    acc += vv[h + 2] * tanh_fast(pv[h + 2] + cv.z);
    acc += vv[h + 3] * tanh_fast(pv[h + 3] + cv.w);
  }
  size_t o = ((size_t)b << 16) + ((size_t)i << 8) + (size_t)t;
  out[o] = acc;
  out[(1u << 20) + o] = (acc >= 0.f) ? 1.f : 0.f;
}

// --------------------------------------------------------------- launch ----
extern "C" void kernel_launch(void* const* d_in, const int* in_sizes, int n_in,
                              void* d_out, int out_size, void* d_ws, size_t ws_size,
                              hipStream_t stream) {
  const int*   concepts = (const int*)d_in[0];
  // d_in[1] = concepts_lengths (all == S, unused)
  const float* emb  = (const float*)d_in[2];
  const float* w_ih = (const float*)d_in[3];   // [2][2][1024][512]
  const float* w_hh = (const float*)d_in[4];   // [2][2][1024][256]
  const float* bias = (const float*)d_in[5];   // [2][2][1024]
  const float* Ua   = (const float*)d_in[6];   // [128][512]
  const float* Wa   = (const float*)d_in[7];   // [128][512]
  const float* va   = (const float*)d_in[8];   // [1][128]
  float* out = (float*)d_out;
  float* ws  = (float*)d_ws;

  constexpr size_t OFF_X   = 0;
  constexpr size_t OFF_G   = OFF_X  + (size_t)M_ * E_;
  constexpr size_t OFF_H0  = OFF_G  + (size_t)M_ * 2048;
  constexpr size_t OFF_H1  = OFF_H0 + (size_t)M_ * 512;
  constexpr size_t OFF_P   = OFF_H1 + (size_t)M_ * 512;
  constexpr size_t OFF_C   = OFF_P  + (size_t)M_ * HM_;
  constexpr size_t OFF_HB  = OFF_C  + (size_t)M_ * HM_;   // u64[2 layers][2d][2par][4096]
  constexpr size_t OFF_CNT = OFF_HB + 2 * (2 * 2 * 4096) * 2;  // u64 -> 2 floats each

  float* X  = ws + OFF_X;
  float* G  = ws + OFF_G;
  float* H0 = ws + OFF_H0;
  float* H1 = ws + OFF_H1;
  float* Pm = ws + OFF_P;
  float* Cm = ws + OFF_C;
  unsigned long long* Hb0 = (unsigned long long*)(ws + OFF_HB);
  unsigned long long* Hb1 = Hb0 + 2 * 2 * 4096;
  int* cnt = (int*)(ws + OFF_CNT);             // [layer][2]

  hipMemsetAsync(cnt, 0, 4 * sizeof(int), stream);

  k_gather<<<M_, 128, 0, stream>>>(concepts, emb, X);

  // layer 0
  k_gemm<<<dim3(32, 16), 256, 0, stream>>>(X, w_ih, bias, G, M_, 2048, 512);
  k_lstm<<<512, 256, 0, stream>>>(G, w_hh, H0, Hb0, cnt);

  // layer 1
  k_gemm<<<dim3(32, 16), 256, 0, stream>>>(H0, w_ih + (size_t)2048 * 512, bias + 2048,
                                           G, M_, 2048, 512);
  k_lstm<<<512, 256, 0, stream>>>(G, w_hh + (size_t)2048 * 256, H1, Hb1, cnt + 2);

  // attention projections
  k_gemm<<<dim3(32, 1), 256, 0, stream>>>(H1, Ua, nullptr, Pm, M_, HM_, 512);
  k_gemm<<<dim3(32, 1), 256, 0, stream>>>(H1, Wa, nullptr, Cm, M_, HM_, 512);

  // fused pairwise scores + predictions
  k_attn<<<M_, 256, 0, stream>>>(Pm, Cm, va, out);
}

// Round 7
// 1551.210 us; speedup vs baseline: 2.5950x; 2.5950x over previous
//
#include <hip/hip_runtime.h>

// ---------------------------------------------------------------------------
// HeadsSelection: emb-gather -> 2x bidirectional LSTM -> additive attention
// S=256, B=16, V=20000, E=512, H=256, L=2, HM=128
// Round 7: R4 exchange protocol restored (R6's XCD co-location is placement-
// fragile: 33ms outlier). New:
//   - k_lstm: 512 thr (8 staging waves -> 8 u64 loads/lane per poll round,
//     half R4's drain), wave-rotated load offsets, row-major Gin (R5 layout).
//     Emits H packed (split-bf16 u32) as a by-product for the next GEMM.
//   - Big input GEMMs now split-bf16 3-product MFMA (k_gemm_pk, 128x128
//     tiles) using the lstm-verified fragment/C layouts. Inputs pre-packed:
//     gather packs X directly; k_pack packs w_ih once.
//   - Workspace layout byte-identical to R4 (63.2 MB) via aliasing.
// ---------------------------------------------------------------------------

#define S_    256
#define B_    16
#define E_    512
#define H_    256
#define HM_   128
#define M_    4096   // S*B

typedef __attribute__((ext_vector_type(8))) short short8;
typedef __attribute__((ext_vector_type(4))) float f32x4;
union u32x4s8 { unsigned int u[4]; uint4 u4; short8 v; };

__device__ __forceinline__ float sigm(float x) { return 1.f / (1.f + __expf(-x)); }
__device__ __forceinline__ float tanh_fast(float x) {
  x = fminf(fmaxf(x, -15.f), 15.f);
  float e = __expf(2.f * x);
  return (e - 1.f) / (e + 1.f);
}
__device__ __forceinline__ unsigned short f2bf(float f) {
  unsigned u = __float_as_uint(f);
  u += 0x7FFFu + ((u >> 16) & 1u);
  return (unsigned short)(u >> 16);
}
__device__ __forceinline__ float bf2f(unsigned short s) {
  return __uint_as_float(((unsigned)s) << 16);
}
// pack float -> {low16: main bf16, high16: residual bf16}
__device__ __forceinline__ unsigned int packsplit(float f) {
  unsigned short m = f2bf(f);
  unsigned short r = f2bf(f - bf2f(m));
  return (unsigned)m | ((unsigned)r << 16);
}

// ---------------------------------------------------------------- gather ----
// gathers embedding rows and packs to split-bf16 u32 (consumed only by GEMM)
__global__ void k_gather_pk(const int* __restrict__ concepts, const float* __restrict__ emb,
                            unsigned int* __restrict__ Xpk) {
  int m = blockIdx.x;                       // m = s*16 + b
  int tok = concepts[m];
  const float4* src = reinterpret_cast<const float4*>(emb + (size_t)tok * E_);
  uint4* dst = reinterpret_cast<uint4*>(Xpk + (size_t)m * E_);
  for (int i = threadIdx.x; i < E_ / 4; i += blockDim.x) {
    float4 v = src[i];
    uint4 o;
    o.x = packsplit(v.x); o.y = packsplit(v.y); o.z = packsplit(v.z); o.w = packsplit(v.w);
    dst[i] = o;
  }
}

// ------------------------------------------------------------------ pack ----
__global__ void k_pack(const float* __restrict__ in, unsigned int* __restrict__ out, int n4) {
  int i = blockIdx.x * blockDim.x + threadIdx.x;
  if (i < n4) {
    float4 v = reinterpret_cast<const float4*>(in)[i];
    uint4 o;
    o.x = packsplit(v.x); o.y = packsplit(v.y); o.z = packsplit(v.z); o.w = packsplit(v.w);
    reinterpret_cast<uint4*>(out)[i] = o;
  }
}

// ------------------------------------------------------------- MFMA GEMM ----
// C[m][n] = sum_k A[m][k]*W[n][k] + bias[n], A/W packed split-bf16 u32.
// 3-product scheme: Am*Bm + Am*Br + Ar*Bm (~2^-17 rel err).
// WG = 128x128 tile, 4 waves in 2x2, wave = 64x64 (4x4 MFMA 16x16x32 tiles).
// Fragment/C layouts identical to the lstm-verified path.
__global__ __launch_bounds__(256) void k_gemm_pk(const unsigned int* __restrict__ Apk,
                                                 const unsigned int* __restrict__ Wpk,
                                                 const float* __restrict__ bias,
                                                 float* __restrict__ C, int N, int K) {
  __shared__ unsigned int As[128][36];
  __shared__ unsigned int Ws2[128][36];
  const int bm = blockIdx.x * 128, bn = blockIdx.y * 128;
  const int tid = threadIdx.x;
  const int wave = tid >> 6, lane = tid & 63;
  const int wm = (wave >> 1) << 6, wn = (wave & 1) << 6;
  const int l16 = lane & 15, quad = lane >> 4;
  const int r = tid >> 1, cb = (tid & 1) << 4;

  f32x4 acc[4][4];
#pragma unroll
  for (int i = 0; i < 4; ++i)
#pragma unroll
    for (int j = 0; j < 4; ++j) acc[i][j] = (f32x4){0.f, 0.f, 0.f, 0.f};

  for (int k0 = 0; k0 < K; k0 += 32) {
    const unsigned int* pa = Apk + (size_t)(bm + r) * K + k0 + cb;
    const unsigned int* pw = Wpk + (size_t)(bn + r) * K + k0 + cb;
    uint4 a0 = *(const uint4*)pa, a1 = *(const uint4*)(pa + 4),
          a2 = *(const uint4*)(pa + 8), a3 = *(const uint4*)(pa + 12);
    uint4 w0 = *(const uint4*)pw, w1 = *(const uint4*)(pw + 4),
          w2 = *(const uint4*)(pw + 8), w3 = *(const uint4*)(pw + 12);
    __syncthreads();                         // previous iter's frag reads done
    *(uint4*)&As[r][cb] = a0;  *(uint4*)&As[r][cb + 4] = a1;
    *(uint4*)&As[r][cb + 8] = a2; *(uint4*)&As[r][cb + 12] = a3;
    *(uint4*)&Ws2[r][cb] = w0; *(uint4*)&Ws2[r][cb + 4] = w1;
    *(uint4*)&Ws2[r][cb + 8] = w2; *(uint4*)&Ws2[r][cb + 12] = w3;
    __syncthreads();

    short8 Amv[4], Arv[4], Bmv[4], Brv[4];
#pragma unroll
    for (int t = 0; t < 4; ++t) {
      const unsigned int* p = &As[wm + (t << 4) + l16][quad << 3];
      uint4 p0 = *(const uint4*)p, p1 = *(const uint4*)(p + 4);
      u32x4s8 m, rr;
      m.u[0] = __builtin_amdgcn_perm(p0.y, p0.x, 0x05040100u);
      rr.u[0] = __builtin_amdgcn_perm(p0.y, p0.x, 0x07060302u);
      m.u[1] = __builtin_amdgcn_perm(p0.w, p0.z, 0x05040100u);
      rr.u[1] = __builtin_amdgcn_perm(p0.w, p0.z, 0x07060302u);
      m.u[2] = __builtin_amdgcn_perm(p1.y, p1.x, 0x05040100u);
      rr.u[2] = __builtin_amdgcn_perm(p1.y, p1.x, 0x07060302u);
      m.u[3] = __builtin_amdgcn_perm(p1.w, p1.z, 0x05040100u);
      rr.u[3] = __builtin_amdgcn_perm(p1.w, p1.z, 0x07060302u);
      Amv[t] = m.v; Arv[t] = rr.v;
      const unsigned int* pb = &Ws2[wn + (t << 4) + l16][quad << 3];
      uint4 q0 = *(const uint4*)pb, q1 = *(const uint4*)(pb + 4);
      m.u[0] = __builtin_amdgcn_perm(q0.y, q0.x, 0x05040100u);
      rr.u[0] = __builtin_amdgcn_perm(q0.y, q0.x, 0x07060302u);
      m.u[1] = __builtin_amdgcn_perm(q0.w, q0.z, 0x05040100u);
      rr.u[1] = __builtin_amdgcn_perm(q0.w, q0.z, 0x07060302u);
      m.u[2] = __builtin_amdgcn_perm(q1.y, q1.x, 0x05040100u);
      rr.u[2] = __builtin_amdgcn_perm(q1.y, q1.x, 0x07060302u);
      m.u[3] = __builtin_amdgcn_perm(q1.w, q1.z, 0x05040100u);
      rr.u[3] = __builtin_amdgcn_perm(q1.w, q1.z, 0x07060302u);
      Bmv[t] = m.v; Brv[t] = rr.v;
    }
#pragma unroll
    for (int ti = 0; ti < 4; ++ti)
#pragma unroll
      for (int tj = 0; tj < 4; ++tj) {
        acc[ti][tj] = __builtin_amdgcn_mfma_f32_16x16x32_bf16(Amv[ti], Bmv[tj], acc[ti][tj], 0, 0, 0);
        acc[ti][tj] = __builtin_amdgcn_mfma_f32_16x16x32_bf16(Amv[ti], Brv[tj], acc[ti][tj], 0, 0, 0);
        acc[ti][tj] = __builtin_amdgcn_mfma_f32_16x16x32_bf16(Arv[ti], Bmv[tj], acc[ti][tj], 0, 0, 0);
      }
  }

  float bv[4];
#pragma unroll
  for (int tj = 0; tj < 4; ++tj)
    bv[tj] = bias ? bias[bn + wn + (tj << 4) + l16] : 0.f;
#pragma unroll
  for (int ti = 0; ti < 4; ++ti)
#pragma unroll
    for (int rr = 0; rr < 4; ++rr) {
      float* crow = C + (size_t)(bm + wm + (ti << 4) + (quad << 2) + rr) * N + bn + wn + l16;
      crow[0]  = acc[ti][0][rr] + bv[0];
      crow[16] = acc[ti][1][rr] + bv[1];
      crow[32] = acc[ti][2][rr] + bv[2];
      crow[48] = acc[ti][3][rr] + bv[3];
    }
}

// ------------------------------------------------------------- fp32 GEMM ----
// (projections only: N=128) C[m][n] = sum_k A[m][k]*W[n][k], row-major C.
__global__ __launch_bounds__(256) void k_gemm(const float* __restrict__ A,
                                              const float* __restrict__ W,
                                              const float* __restrict__ bias,
                                              float* __restrict__ C,
                                              int M, int N, int K) {
  __shared__ __align__(16) float As[16][132];
  __shared__ __align__(16) float Ws[16][132];
  const int bm = blockIdx.x * 128, bn = blockIdx.y * 128;
  const int tid = threadIdx.x;
  const int tm = (tid >> 4) * 8, tn = (tid & 15) * 8;
  float acc[8][8];
#pragma unroll
  for (int i = 0; i < 8; i++)
#pragma unroll
    for (int j = 0; j < 8; j++) acc[i][j] = 0.f;

  const int lr = tid >> 1, lk = (tid & 1) * 8;
  for (int k0 = 0; k0 < K; k0 += 16) {
    float4 a0 = *(const float4*)(A + (size_t)(bm + lr) * K + k0 + lk);
    float4 a1 = *(const float4*)(A + (size_t)(bm + lr) * K + k0 + lk + 4);
    float4 w0 = *(const float4*)(W + (size_t)(bn + lr) * K + k0 + lk);
    float4 w1 = *(const float4*)(W + (size_t)(bn + lr) * K + k0 + lk + 4);
    As[lk + 0][lr] = a0.x; As[lk + 1][lr] = a0.y; As[lk + 2][lr] = a0.z; As[lk + 3][lr] = a0.w;
    As[lk + 4][lr] = a1.x; As[lk + 5][lr] = a1.y; As[lk + 6][lr] = a1.z; As[lk + 7][lr] = a1.w;
    Ws[lk + 0][lr] = w0.x; Ws[lk + 1][lr] = w0.y; Ws[lk + 2][lr] = w0.z; Ws[lk + 3][lr] = w0.w;
    Ws[lk + 4][lr] = w1.x; Ws[lk + 5][lr] = w1.y; Ws[lk + 6][lr] = w1.z; Ws[lk + 7][lr] = w1.w;
    __syncthreads();
#pragma unroll
    for (int k = 0; k < 16; k++) {
      float4 av0 = *(const float4*)&As[k][tm];
      float4 av1 = *(const float4*)&As[k][tm + 4];
      float4 wv0 = *(const float4*)&Ws[k][tn];
      float4 wv1 = *(const float4*)&Ws[k][tn + 4];
      float a[8] = {av0.x, av0.y, av0.z, av0.w, av1.x, av1.y, av1.z, av1.w};
      float w[8] = {wv0.x, wv0.y, wv0.z, wv0.w, wv1.x, wv1.y, wv1.z, wv1.w};
#pragma unroll
      for (int i = 0; i < 8; i++)
#pragma unroll
        for (int j = 0; j < 8; j++) acc[i][j] += a[i] * w[j];
    }
    __syncthreads();
  }

  float bv[8];
#pragma unroll
  for (int j = 0; j < 8; j++) bv[j] = bias ? bias[bn + tn + j] : 0.f;
#pragma unroll
  for (int i = 0; i < 8; i++) {
    float4 v0 = make_float4(acc[i][0] + bv[0], acc[i][1] + bv[1], acc[i][2] + bv[2], acc[i][3] + bv[3]);
    float4 v1 = make_float4(acc[i][4] + bv[4], acc[i][5] + bv[5], acc[i][6] + bv[6], acc[i][7] + bv[7]);
    *(float4*)(C + (size_t)(bm + tm + i) * N + bn + tn) = v0;
    *(float4*)(C + (size_t)(bm + tm + i) * N + bn + tn + 4) = v1;
  }
}

// ------------------------------------------------------------- LSTM layer ----
// Grid: 32 WGs = dir(2) x g(16), 512 threads (8 waves). Waves 0-3: gate q
// MFMA (16x16x32 split-bf16 3-product, K=256). All 8 waves stage h_prev:
// 8 u64 loads/lane per poll round (half R4's drain), wave-rotated offsets.
// R4 protocol: Hbuf entries are u64 {stamp=it+1, packed h}; single relaxed
// agent-scope store publishes; consumers stamp-validate (no fences).
// Gin: [m][2048] row-major. Houtf: [m][512] f32. Houtp: same idx packed u32.
__global__ __launch_bounds__(512) void k_lstm(const float* __restrict__ Gin,
                                              const float* __restrict__ whh,
                                              float* __restrict__ Houtf,
                                              unsigned int* __restrict__ Houtp,
                                              unsigned long long* __restrict__ Hbuf) {
  const int d = blockIdx.x >> 4;
  const int g = blockIdx.x & 15;
  const int tid = threadIdx.x;
  const int w8 = tid >> 6;         // wave 0..7; waves 0-3 also run MFMA (gate q=w8)
  const int lane = tid & 63;
  const int bcol = lane & 15;      // MFMA A row / C col (batch)
  const int quad = lane >> 4;      // MFMA k-group / C row group
  const int u_e = tid & 15;        // epilogue (tid<256): unit
  const int b_e = (tid >> 4) & 15; // epilogue: batch
  const int ws = (w8 + g) & 7;     // rotated stage offset (spread bursts)
  __shared__ unsigned int hL[16 * 260];           // packed h: [b]*260 + [k]
  __shared__ __align__(16) float Lg[4][16][24];   // [gate][b][unit(+pad)]

  // ---- one-time: A fragments (whh) into VGPRs, split bf16 main+residual ----
  unsigned int Am[8][4], Ar[8][4];
  if (w8 < 4) {
    const float* wrow = whh + (size_t)((d << 10) + (w8 << 8) + (g << 4) + bcol) * 256;
#pragma unroll
    for (int s = 0; s < 8; ++s) {
      float w[8];
      *(float4*)&w[0] = *(const float4*)(wrow + s * 32 + quad * 8);
      *(float4*)&w[4] = *(const float4*)(wrow + s * 32 + quad * 8 + 4);
#pragma unroll
      for (int j = 0; j < 4; ++j) {
        unsigned short m0 = f2bf(w[2 * j]), m1 = f2bf(w[2 * j + 1]);
        unsigned short r0 = f2bf(w[2 * j] - bf2f(m0));
        unsigned short r1 = f2bf(w[2 * j + 1] - bf2f(m1));
        Am[s][j] = (unsigned)m0 | ((unsigned)m1 << 16);
        Ar[s][j] = (unsigned)r0 | ((unsigned)r1 << 16);
      }
    }
  }

  float c_reg = 0.f;
  for (int it = 0; it < 256; ++it) {
    const int step = d ? (255 - it) : it;

    // ---- Gin prefetch (independent of h; row-major coalesced) ----
    float gin[4];
    if (tid < 256) {
#pragma unroll
      for (int qq = 0; qq < 4; ++qq)
        gin[qq] = Gin[((size_t)((step << 4) + b_e) << 11) + (d << 10) + (qq << 8) + (g << 4) + u_e];
    }

    // ---- stage h_prev: 8 u64 loads/lane, stamp-retry, write LDS ----
    if (it > 0) {
      const unsigned long long* src = Hbuf + ((size_t)((d << 1) + ((it - 1) & 1)) << 12);
      const unsigned long long* p0 = src + (ws << 9) + lane;
      const unsigned int want = (unsigned int)it;
      unsigned long long v[8];
#pragma unroll
      for (int c = 0; c < 8; ++c)
        v[c] = __hip_atomic_load(p0 + (c << 6), __ATOMIC_RELAXED, __HIP_MEMORY_SCOPE_AGENT);
      for (;;) {
        unsigned int badm = 0;
#pragma unroll
        for (int c = 0; c < 8; ++c)
          badm |= ((unsigned int)(v[c] >> 32) != want) ? (1u << c) : 0u;
        if (__ballot(badm != 0) == 0ull) break;
#pragma unroll
        for (int c = 0; c < 8; ++c)
          if (badm & (1u << c))
            v[c] = __hip_atomic_load(p0 + (c << 6), __ATOMIC_RELAXED, __HIP_MEMORY_SCOPE_AGENT);
      }
#pragma unroll
      for (int c = 0; c < 8; ++c) {
        int e_b = (ws << 1) + (c >> 2);            // entry e = ws*512+c*64+lane
        int e_k = ((c & 3) << 6) + lane;           //        = b*256+k
        hL[e_b * 260 + e_k] = (unsigned int)v[c];
      }
    }
    __syncthreads();

    // ---- B fragments from LDS, 3-product split MFMA (waves 0-3) ----
    if (w8 < 4) {
      f32x4 acc0 = {0.f, 0.f, 0.f, 0.f}, acc1 = acc0, acc2 = acc0;
      if (it > 0) {
#pragma unroll
        for (int s = 0; s < 8; ++s) {
          const unsigned int* p = &hL[bcol * 260 + (s << 5) + (quad << 3)];
          uint4 p0v = *(const uint4*)p;
          uint4 p1v = *(const uint4*)(p + 4);
          u32x4s8 Bm, Br, Amu, Aru;
          Bm.u[0] = __builtin_amdgcn_perm(p0v.y, p0v.x, 0x05040100u);
          Br.u[0] = __builtin_amdgcn_perm(p0v.y, p0v.x, 0x07060302u);
          Bm.u[1] = __builtin_amdgcn_perm(p0v.w, p0v.z, 0x05040100u);
          Br.u[1] = __builtin_amdgcn_perm(p0v.w, p0v.z, 0x07060302u);
          Bm.u[2] = __builtin_amdgcn_perm(p1v.y, p1v.x, 0x05040100u);
          Br.u[2] = __builtin_amdgcn_perm(p1v.y, p1v.x, 0x07060302u);
          Bm.u[3] = __builtin_amdgcn_perm(p1v.w, p1v.z, 0x05040100u);
          Br.u[3] = __builtin_amdgcn_perm(p1v.w, p1v.z, 0x07060302u);
#pragma unroll
          for (int j = 0; j < 4; ++j) { Amu.u[j] = Am[s][j]; Aru.u[j] = Ar[s][j]; }
          acc0 = __builtin_amdgcn_mfma_f32_16x16x32_bf16(Amu.v, Bm.v, acc0, 0, 0, 0);
          acc1 = __builtin_amdgcn_mfma_f32_16x16x32_bf16(Amu.v, Br.v, acc1, 0, 0, 0);
          acc2 = __builtin_amdgcn_mfma_f32_16x16x32_bf16(Aru.v, Bm.v, acc2, 0, 0, 0);
        }
      }
      f32x4 t = acc0 + acc1 + acc2;
      *(float4*)&Lg[w8][bcol][quad << 2] = make_float4(t[0], t[1], t[2], t[3]);
    }
    __syncthreads();

    // ---- nonlinearity + state update; fire-and-forget publish ----
    if (tid < 256) {
      float gi = Lg[0][b_e][u_e] + gin[0];
      float gf = Lg[1][b_e][u_e] + gin[1];
      float gg = Lg[2][b_e][u_e] + gin[2];
      float go = Lg[3][b_e][u_e] + gin[3];
      float ct = sigm(gf) * c_reg + sigm(gi) * tanh_fast(gg);
      c_reg = ct;
      float h = sigm(go) * tanh_fast(ct);
      unsigned short hm = f2bf(h);
      unsigned short hr = f2bf(h - bf2f(hm));
      unsigned int hpk = ((unsigned)hr << 16) | (unsigned)hm;
      unsigned long long hp = ((unsigned long long)(unsigned int)(it + 1) << 32) |
                              (unsigned long long)hpk;
      __hip_atomic_store(Hbuf + ((size_t)((d << 1) + (it & 1)) << 12) + (b_e << 8) + (g << 4) + u_e,
                         hp, __ATOMIC_RELAXED, __HIP_MEMORY_SCOPE_AGENT);
      size_t oidx = (size_t)((step << 4) + b_e) * 512 + (d << 8) + (g << 4) + u_e;
      Houtf[oidx] = h;
      Houtp[oidx] = hpk;
    }
    // no drain barrier: consumers validate stamps themselves.
  }
}

// ------------------------------------------------------------- attention ----
// scores[b][i][j] = sum_h va[h]*tanh(P[i*16+b][h] + Cc[j*16+b][h])
// out[0 .. 1M) = scores; out[1M .. 2M) = predictions (sigmoid>=0.5 <=> x>=0)
__global__ __launch_bounds__(256) void k_attn(const float* __restrict__ P,
                                              const float* __restrict__ Cc,
                                              const float* __restrict__ va,
                                              float* __restrict__ out) {
  const int b = blockIdx.x & 15, i = blockIdx.x >> 4;
  __shared__ float pv[128], vv[128];
  const int t = threadIdx.x;
  if (t < 128) {
    pv[t] = P[(size_t)((i << 4) + b) * 128 + t];
    vv[t] = va[t];
  }
  __syncthreads();
  const float4* c4 = reinterpret_cast<const float4*>(Cc + (size_t)((t << 4) + b) * 128);
  float acc = 0.f;
#pragma unroll 8
  for (int hh = 0; hh < 32; ++hh) {
    float4 cv = c4[hh];
    int h = hh << 2;
    acc += vv[h]     * tanh_fast(pv[h]     + cv.x);
    acc += vv[h + 1] * tanh_fast(pv[h + 1] + cv.y);
    acc += vv[h + 2] * tanh_fast(pv[h + 2] + cv.z);
    acc += vv[h + 3] * tanh_fast(pv[h + 3] + cv.w);
  }
  size_t o = ((size_t)b << 16) + ((size_t)i << 8) + (size_t)t;
  out[o] = acc;
  out[(1u << 20) + o] = (acc >= 0.f) ? 1.f : 0.f;
}

// --------------------------------------------------------------- launch ----
extern "C" void kernel_launch(void* const* d_in, const int* in_sizes, int n_in,
                              void* d_out, int out_size, void* d_ws, size_t ws_size,
                              hipStream_t stream) {
  const int*   concepts = (const int*)d_in[0];
  // d_in[1] = concepts_lengths (all == S, unused)
  const float* emb  = (const float*)d_in[2];
  const float* w_ih = (const float*)d_in[3];   // [2][2][1024][512]
  const float* w_hh = (const float*)d_in[4];   // [2][2][1024][256]
  const float* bias = (const float*)d_in[5];   // [2][2][1024]
  const float* Ua   = (const float*)d_in[6];   // [128][512]
  const float* Wa   = (const float*)d_in[7];   // [128][512]
  const float* va   = (const float*)d_in[8];   // [1][128]
  float* out = (float*)d_out;
  float* ws  = (float*)d_ws;

  // workspace (floats) — total 15,794,176 floats = byte-identical to R4 usage
  constexpr size_t OFF_G   = 0;                               // [4096][2048] f32
  constexpr size_t OFF_PK  = OFF_G  + (size_t)M_ * 2048;      // Xpk/H0pk/H1pk u32 [4096][512]
  constexpr size_t OFF_WPK = OFF_PK + (size_t)M_ * 512;       // Wpk u32 [2][2048][512]
  constexpr size_t OFF_HF  = OFF_WPK + 2 * 2048 * 512;        // H f32 [4096][512]
  constexpr size_t OFF_P   = OFF_HF + (size_t)M_ * 512;       // Pm [4096][128]
  constexpr size_t OFF_C   = OFF_P  + (size_t)M_ * HM_;       // Cm [4096][128]
  constexpr size_t OFF_HB  = OFF_C  + (size_t)M_ * HM_;       // Hbuf u64 x2 layers

  float* G  = ws + OFF_G;
  unsigned int* PK  = (unsigned int*)(ws + OFF_PK);
  unsigned int* WPK = (unsigned int*)(ws + OFF_WPK);
  float* HF = ws + OFF_HF;
  float* Pm = ws + OFF_P;
  float* Cm = ws + OFF_C;
  unsigned long long* Hb0 = (unsigned long long*)(ws + OFF_HB);
  unsigned long long* Hb1 = Hb0 + 2 * 2 * 4096;

  // pack w_ih (both layers) once; gather packs X directly
  k_pack<<<(2 * 2048 * 512 / 4 + 255) / 256, 256, 0, stream>>>(w_ih, WPK, 2 * 2048 * 512 / 4);
  k_gather_pk<<<M_, 128, 0, stream>>>(concepts, emb, PK);

  // layer 0: Gin GEMM (MFMA split-bf16) then recurrence (writes H0 packed into PK)
  k_gemm_pk<<<dim3(32, 16), 256, 0, stream>>>(PK, WPK, bias, G, 2048, 512);
  k_lstm<<<32, 512, 0, stream>>>(G, w_hh, HF, PK, Hb0);   // PK now = H0pk (Xpk dead)

  // layer 1
  k_gemm_pk<<<dim3(32, 16), 256, 0, stream>>>(PK, WPK + (size_t)2048 * 512, bias + 2048,
                                              G, 2048, 512);
  k_lstm<<<32, 512, 0, stream>>>(G, w_hh + (size_t)2048 * 256, HF, PK, Hb1);  // HF = H1 f32

  // attention projections (fp32; small)
  k_gemm<<<dim3(32, 1), 256, 0, stream>>>(HF, Ua, nullptr, Pm, M_, HM_, 512);
  k_gemm<<<dim3(32, 1), 256, 0, stream>>>(HF, Wa, nullptr, Cm, M_, HM_, 512);

  // fused pairwise scores + predictions
  k_attn<<<M_, 256, 0, stream>>>(Pm, Cm, va, out);
}